// Round 9
// baseline (285.360 us; speedup 1.0000x reference)
//
#include <hip/hip_runtime.h>
#include <hip/hip_bf16.h>

// ExpertBank MoE FFN on gfx950 — round 18.
// r17 post-mortem: 4-deep FAILED (gemm2 47->58.4us, Occ 5.7%, VGPR 132): 1 blk/CU ILP
// cannot replace 2 blk/CU TLP (confirmed twice w/ r15). gemm2 reverted to r13-exact
// 2-deep/66KB/(256,2). Remaining gap (both GEMMs ~47-50 vs ~27us request floor) =
// staging-latency exposure. r18 lever: T1 XCD co-location via GRID AXIS SWAP (x=mt,y=nt):
// blocks sharing an A-panel get linear ids mt+64k == mt (mod 8) -> same XCD -> A-panels
// L2-resident (8x512KB fits 4MB), A fetched from HBM once chip-wide, staging hits go
// LLC/HBM(500-900cy) -> L2(~200cy), which the 2-deep pipeline CAN cover.
// Falsifier: if gemm2 FETCH (74-82MB) doesn't drop toward ~55, drop the swizzle.
// ws: int[0..7] counts, [16..23] opad, [32..) rowmap(9216),
//     byte 65536: H bf16 [9216][2048] (37.75 MB), Xb bf16 (4.2 MB),
//     W1T bf16 (16.8 MB), [optional] W2T bf16 (16.8 MB).

typedef __bf16 bf16x8 __attribute__((ext_vector_type(8)));
typedef float f32x4 __attribute__((ext_vector_type(4)));

#define DM 512
#define DF 2048
#define NE 8
#define NTOK 4096
#define NPAIR 8192
#define HCAP 9216

__device__ __forceinline__ unsigned short f2bf(float x) {
    unsigned u = __builtin_bit_cast(unsigned, x);
    return (unsigned short)((u + 0x7fffu + ((u >> 16) & 1u)) >> 16);
}
__device__ __forceinline__ unsigned pack2(float lo, float hi) {
    return (unsigned)f2bf(lo) | ((unsigned)f2bf(hi) << 16);
}
// tanh-form GELU == x*sigmoid(2y); log2e folded: gelu = x * rcp(1 + exp2(z)). |err|~3e-4.
__device__ __forceinline__ float gelu_fast(float x) {
    float x2 = x * x;
    float z = x * __builtin_fmaf(x2, -0.1029432f, -2.3022083f);
    float e = __builtin_amdgcn_exp2f(z);
    return x * __builtin_amdgcn_rcpf(1.0f + e);
}
// async 16B global->LDS (gfx950); lds pointer must be wave-uniform, writes lane*16B
__device__ __forceinline__ void dma16(const unsigned short* g, unsigned short* l) {
    __builtin_amdgcn_global_load_lds(
        (const __attribute__((address_space(1))) void*)g,
        (__attribute__((address_space(3))) void*)l, 16, 0, 0);
}
// BK=64 tile [128][64] bf16: 8 16B-chunks per 128B row; XOR swizzle chunk^(row&7).
__device__ __forceinline__ int slot64(int row, int c) { return row * 8 + (c ^ (row & 7)); }

// one 128x128x64 MFMA step (2 x K=32 sub-steps) from swizzled LDS tiles
__device__ __forceinline__ void mfma_step(const unsigned short* Ab, const unsigned short* Bb,
                                          int wm, int wn, int quad, int l15,
                                          f32x4 (&acc)[4][4]) {
#pragma unroll
    for (int kk = 0; kk < 2; ++kk) {
        const int c = kk * 4 + quad;
        bf16x8 a[4], b[4];
#pragma unroll
        for (int fm = 0; fm < 4; ++fm) {
            int row = wm * 64 + fm * 16 + l15;
            a[fm] = __builtin_bit_cast(bf16x8, *(const uint4*)&Ab[slot64(row, c) * 8]);
        }
#pragma unroll
        for (int fn = 0; fn < 4; ++fn) {
            int row = wn * 64 + fn * 16 + l15;
            b[fn] = __builtin_bit_cast(bf16x8, *(const uint4*)&Bb[slot64(row, c) * 8]);
        }
#pragma unroll
        for (int fm = 0; fm < 4; ++fm)
#pragma unroll
            for (int fn = 0; fn < 4; ++fn)
                acc[fm][fn] = __builtin_amdgcn_mfma_f32_16x16x32_bf16(a[fm], b[fn], acc[fm][fn], 0, 0, 0);
    }
}

// 8 dma16 per wave per STAGE (4 A + 4 B); ko in ushort elements; buf stride 8192 ushorts
#define STAGE(buf, ko)                                        \
    do {                                                      \
        _Pragma("unroll") for (int j_ = 0; j_ < 4; ++j_) {    \
            dma16(ga[j_] + (ko), la[j_] + (buf) * 8192);      \
            dma16(gb[j_] + (ko), lb[j_] + (buf) * 8192);      \
        }                                                     \
    } while (0)

#define WAITN(n)                                                  \
    do {                                                          \
        __builtin_amdgcn_sched_barrier(0);                        \
        asm volatile("s_waitcnt vmcnt(" #n ")" ::: "memory");     \
        __builtin_amdgcn_sched_barrier(0);                        \
    } while (0)

#define BAR() __builtin_amdgcn_s_barrier()

// ---- mega-prep: 0 routing, [1,1025) cvtX, [1025,3073) tw(W1),
// ----            [3073,5121) tw(W2)  (only dispatched in fused mode) ----
__global__ void k_prep(const float* __restrict__ X, unsigned short* __restrict__ Xb,
                       const float* __restrict__ W1, unsigned short* __restrict__ W1T,
                       const float* __restrict__ W2, unsigned short* __restrict__ W2T,
                       const int* __restrict__ sel, int* __restrict__ counts_g,
                       int* __restrict__ opad_g, int* __restrict__ rowmap,
                       float* __restrict__ loads_out) {
    __shared__ unsigned short T[64][65];
    __shared__ int hist[NE], cur[NE], off[NE];
    const int b = blockIdx.x, tid = threadIdx.x;

    if (b == 0) {  // routing FIRST (block 0): histogram + padded scan + compact assign
        if (tid < NE) { hist[tid] = 0; cur[tid] = 0; }
        __syncthreads();
#pragma unroll
        for (int i = 0; i < NPAIR / 256; ++i)
            atomicAdd(&hist[sel[i * 256 + tid]], 1);
        __syncthreads();
        if (tid == 0) {
            int s = 0;
            for (int e = 0; e < NE; ++e) {
                off[e] = s;
                s += (hist[e] + 127) & ~127;
                counts_g[e] = hist[e];
                opad_g[e] = off[e];
                loads_out[e] = (float)hist[e] * (1.0f / (float)NTOK);
            }
        }
        __syncthreads();
#pragma unroll
        for (int i = 0; i < NPAIR / 256; ++i) {
            int p = i * 256 + tid;
            int e = sel[p];
            int pos = atomicAdd(&cur[e], 1);
            rowmap[off[e] + pos] = p;
        }
    } else if (b < 1025) {  // X fp32 -> bf16
        int i = ((b - 1) * 256 + tid) * 8;
        float4 a = *(const float4*)(X + i);
        float4 c = *(const float4*)(X + i + 4);
        uint4 u;
        u.x = pack2(a.x, a.y); u.y = pack2(a.z, a.w);
        u.z = pack2(c.x, c.y); u.w = pack2(c.z, c.w);
        *(uint4*)(Xb + i) = u;
    } else if (b < 3073) {  // W1 [E][DM][DF] -> bf16 W1T [E][DF][DM]
        const int t = b - 1025;
        const int bx = t & 31, by = (t >> 5) & 7, bz = t >> 8;
        const int tx = tid & 15, ty = tid >> 4;
        const int r0 = by * 64, c0 = bx * 64;
        const float* src = W1 + ((size_t)bz * DM + r0) * DF + c0;
#pragma unroll
        for (int i = 0; i < 4; ++i) {
            int r = ty + i * 16;
            float4 v = *(const float4*)(src + (size_t)r * DF + tx * 4);
            T[tx * 4 + 0][r] = f2bf(v.x); T[tx * 4 + 1][r] = f2bf(v.y);
            T[tx * 4 + 2][r] = f2bf(v.z); T[tx * 4 + 3][r] = f2bf(v.w);
        }
        __syncthreads();
        unsigned short* dst = W1T + ((size_t)bz * DF + c0) * DM + r0;
#pragma unroll
        for (int i = 0; i < 4; ++i) {
            int c = ty + i * 16;
            ushort4 w;
            w.x = T[c][tx * 4 + 0]; w.y = T[c][tx * 4 + 1];
            w.z = T[c][tx * 4 + 2]; w.w = T[c][tx * 4 + 3];
            *(ushort4*)(dst + (size_t)c * DM + tx * 4) = w;
        }
    } else {  // W2 [E][DF][DM] -> bf16 W2T [E][DM][DF] (fused mode only)
        const int t = b - 3073;
        const int bx = t & 7, by = (t >> 3) & 31, bz = t >> 8;
        const int tx = tid & 15, ty = tid >> 4;
        const int r0 = by * 64, c0 = bx * 64;
        const float* src = W2 + ((size_t)bz * DF + r0) * DM + c0;
#pragma unroll
        for (int i = 0; i < 4; ++i) {
            int r = ty + i * 16;
            float4 v = *(const float4*)(src + (size_t)r * DM + tx * 4);
            T[tx * 4 + 0][r] = f2bf(v.x); T[tx * 4 + 1][r] = f2bf(v.y);
            T[tx * 4 + 2][r] = f2bf(v.z); T[tx * 4 + 3][r] = f2bf(v.w);
        }
        __syncthreads();
        unsigned short* dst = W2T + ((size_t)bz * DM + c0) * DF + r0;
#pragma unroll
        for (int i = 0; i < 4; ++i) {
            int c = ty + i * 16;
            ushort4 w;
            w.x = T[c][tx * 4 + 0]; w.y = T[c][tx * 4 + 1];
            w.z = T[c][tx * 4 + 2]; w.w = T[c][tx * 4 + 3];
            *(ushort4*)(dst + (size_t)c * DF + tx * 4) = w;
        }
    }
}

// ---- W2 [E][DF][DM] -> bf16 W2T [E][DM][DF] (fallback when ws too small to fuse) ----
__global__ void k_tw2(const float* __restrict__ in, unsigned short* __restrict__ out) {
    __shared__ unsigned short T[64][65];
    const int tid = threadIdx.x;
    const int tx = tid & 15, ty = tid >> 4;
    const int r0 = blockIdx.y * 64, c0 = blockIdx.x * 64;
    const float* src = in + ((size_t)blockIdx.z * DF + r0) * DM + c0;
#pragma unroll
    for (int i = 0; i < 4; ++i) {
        int r = ty + i * 16;
        float4 v = *(const float4*)(src + (size_t)r * DM + tx * 4);
        T[tx * 4 + 0][r] = f2bf(v.x); T[tx * 4 + 1][r] = f2bf(v.y);
        T[tx * 4 + 2][r] = f2bf(v.z); T[tx * 4 + 3][r] = f2bf(v.w);
    }
    __syncthreads();
    unsigned short* dst = out + ((size_t)blockIdx.z * DM + c0) * DF + r0;
#pragma unroll
    for (int i = 0; i < 4; ++i) {
        int c = ty + i * 16;
        ushort4 w;
        w.x = T[c][tx * 4 + 0]; w.y = T[c][tx * 4 + 1];
        w.z = T[c][tx * 4 + 2]; w.w = T[c][tx * 4 + 3];
        *(ushort4*)(dst + (size_t)c * DF + tx * 4) = w;
    }
}

// ---------------- GEMM1: H = gelu(Xb[tok] @ W1), 128x128, BK=64, dbuf counted-vmcnt ----
// r14-exact except grid axes swapped: x=mt, y=nt (XCD co-location of shared-A blocks).
__launch_bounds__(256, 2)
__global__ void k_gemm1d(const unsigned short* __restrict__ Xb,
                         const unsigned short* __restrict__ W1T,
                         const int* __restrict__ counts, const int* __restrict__ opad,
                         const int* __restrict__ rowmap, unsigned short* __restrict__ H) {
    const int e = blockIdx.z, mt = blockIdx.x, nt = blockIdx.y;
    const int grow = opad[e] + mt * 128;
    int valid = counts[e] - mt * 128;
    if (valid <= 0) return;
    if (valid > 128) valid = 128;

    __shared__ __align__(16) unsigned short SM[4][8192];
    __shared__ int toks[128];

    const int tid = threadIdx.x;
    if (tid < 128) {
        int i = (tid < valid) ? tid : 0;
        toks[tid] = rowmap[grow + i] >> 1;
    }
    __syncthreads();

    const int wave = tid >> 6, lane = tid & 63;
    const int wm = wave >> 1, wn = wave & 1;
    const int quad = lane >> 4, l15 = lane & 15;

    const unsigned short* ga[4];
    const unsigned short* gb[4];
    unsigned short* la[4];
    unsigned short* lb[4];
#pragma unroll
    for (int j = 0; j < 4; ++j) {
        int row = wave * 32 + j * 8 + (lane >> 3);
        int ch = (lane & 7) ^ ((lane >> 3) & 7);
        ga[j] = Xb + (size_t)toks[row] * DM + ch * 8;
        gb[j] = W1T + ((size_t)e * DF + nt * 128 + row) * DM + ch * 8;
        la[j] = &SM[0][(wave * 32 + j * 8) * 64];
        lb[j] = &SM[2][(wave * 32 + j * 8) * 64];
    }

    f32x4 acc[4][4] = {};

    STAGE(0, 0);
#pragma unroll 1
    for (int kt = 0; kt < 8; kt += 2) {
        if (kt + 1 < 8) { STAGE(1, (kt + 1) * 64); WAITN(8); } else { WAITN(0); }
        BAR();
        mfma_step(&SM[0][0], &SM[2][0], wm, wn, quad, l15, acc);
        BAR();
        if (kt + 2 < 8) { STAGE(0, (kt + 2) * 64); WAITN(8); } else { WAITN(0); }
        BAR();
        mfma_step(&SM[1][0], &SM[3][0], wm, wn, quad, l15, acc);
        BAR();
    }

    // ---- epilogue through LDS: bf16 C-tile [128][136], then coalesced 16B stores ----
    unsigned short* ep = &SM[0][0];
#pragma unroll
    for (int fm = 0; fm < 4; ++fm)
#pragma unroll
        for (int i = 0; i < 4; ++i) {
            int r = wm * 64 + fm * 16 + quad * 4 + i;
#pragma unroll
            for (int fn = 0; fn < 4; ++fn)
                ep[r * 136 + wn * 64 + fn * 16 + l15] = f2bf(gelu_fast(acc[fm][fn][i]));
        }
    __syncthreads();
    {
        const int rr0 = tid >> 4, ch = tid & 15;
#pragma unroll
        for (int it = 0; it < 8; ++it) {
            int r = it * 16 + rr0;
            uint4 v = *(const uint4*)&ep[r * 136 + ch * 8];
            *(uint4*)(H + (size_t)(grow + r) * DF + nt * 128 + ch * 8) = v;
        }
    }
}

// ------- GEMM2: out = H @ W2 (K=2048, plain stores), 128x128, 2-deep (r13-exact) -------
// Grid axes swapped: x=mt, y=nt (XCD co-location of shared-A blocks).
__launch_bounds__(256, 2)
__global__ void k_gemm2d(const unsigned short* __restrict__ H,
                         const unsigned short* __restrict__ W2T,
                         const int* __restrict__ counts, const int* __restrict__ opad,
                         const int* __restrict__ rowmap, float* __restrict__ out) {
    const int e = blockIdx.z, mt = blockIdx.x, nt = blockIdx.y;
    const int grow = opad[e] + mt * 128;
    int valid = counts[e] - mt * 128;
    if (valid <= 0) return;
    if (valid > 128) valid = 128;

    __shared__ __align__(16) unsigned short As[2][8192];
    __shared__ __align__(16) unsigned short Bs[2][8192];
    __shared__ int pairs[128];

    const int tid = threadIdx.x;
    if (tid < 128) pairs[tid] = (tid < valid) ? rowmap[grow + tid] : 0;
    __syncthreads();

    const int wave = tid >> 6, lane = tid & 63;
    const int wm = wave >> 1, wn = wave & 1;
    const int quad = lane >> 4, l15 = lane & 15;

    const unsigned short* ga[4];
    const unsigned short* gb[4];
    unsigned short* la[4];
    unsigned short* lb[4];
#pragma unroll
    for (int j = 0; j < 4; ++j) {
        int row = wave * 32 + j * 8 + (lane >> 3);
        int ch = (lane & 7) ^ ((lane >> 3) & 7);
        int rr = (row < valid) ? row : 0;  // clamp: never read unwritten H (r7 lesson)
        ga[j] = H + (size_t)(grow + rr) * DF + ch * 8;
        gb[j] = W2T + ((size_t)e * DM + nt * 128 + row) * DF + ch * 8;
        la[j] = &As[0][(wave * 32 + j * 8) * 64];
        lb[j] = &Bs[0][(wave * 32 + j * 8) * 64];
    }

    f32x4 acc[4][4] = {};

    STAGE(0, 0);
#pragma unroll 1
    for (int kt = 0; kt < 32; kt += 2) {
        if (kt + 1 < 32) { STAGE(1, (kt + 1) * 64); WAITN(8); } else { WAITN(0); }
        BAR();
        mfma_step(&As[0][0], &Bs[0][0], wm, wn, quad, l15, acc);
        BAR();
        if (kt + 2 < 32) { STAGE(0, (kt + 2) * 64); WAITN(8); } else { WAITN(0); }
        BAR();
        mfma_step(&As[1][0], &Bs[1][0], wm, wn, quad, l15, acc);
        BAR();
    }

#pragma unroll
    for (int fm = 0; fm < 4; ++fm) {
#pragma unroll
        for (int i = 0; i < 4; ++i) {
            int m_l = wm * 64 + fm * 16 + quad * 4 + i;
            if (m_l < valid) {
                float* orow = out + (size_t)pairs[m_l] * DM + nt * 128 + wn * 64;
#pragma unroll
                for (int fn = 0; fn < 4; ++fn)
                    orow[fn * 16 + l15] = acc[fm][fn][i];  // exactly-once: plain store
            }
        }
    }
}

extern "C" void kernel_launch(void* const* d_in, const int* in_sizes, int n_in,
                              void* d_out, int out_size, void* d_ws, size_t ws_size,
                              hipStream_t stream) {
    const float* X = (const float*)d_in[0];
    const int* sel = (const int*)d_in[1];
    const float* W1 = (const float*)d_in[3];
    const float* W2 = (const float*)d_in[4];
    float* out = (float*)d_out;
    float* loads_out = out + (size_t)NPAIR * DM;

    int* counts = (int*)d_ws;
    int* opad = counts + 16;
    int* rowmap = counts + 32;
    const size_t hbytes = (size_t)HCAP * DF * 2;
    const size_t xbytes = (size_t)NTOK * DM * 2;
    const size_t w1tbytes = (size_t)NE * DF * DM * 2;
    unsigned short* H = (unsigned short*)((char*)d_ws + 65536);
    unsigned short* Xb = (unsigned short*)((char*)d_ws + 65536 + hbytes);
    unsigned short* WT = (unsigned short*)((char*)d_ws + 65536 + hbytes + xbytes);

    // fused mode: separate W2T buffer -> W2 transpose folds into k_prep, no k_tw2 dispatch
    const bool fused = ws_size >= 65536 + hbytes + xbytes + 2 * w1tbytes;
    unsigned short* W2T = fused ? WT + w1tbytes / 2 : WT;

    hipLaunchKernelGGL(k_prep, dim3(fused ? 5121 : 3073), dim3(256), 0, stream,
                       X, Xb, W1, WT, W2, W2T, sel, counts, opad, rowmap, loads_out);
    hipLaunchKernelGGL(k_gemm1d, dim3(NPAIR / 128, DF / 128, NE), dim3(256), 0, stream,
                       Xb, WT, counts, opad, rowmap, H);
    if (!fused)
        hipLaunchKernelGGL(k_tw2, dim3(DM / 64, DF / 64, NE), dim3(256), 0, stream, W2, WT);
    hipLaunchKernelGGL(k_gemm2d, dim3(NPAIR / 128, 4, NE), dim3(256), 0, stream,
                       H, W2T, counts, opad, rowmap, out);
}

// Round 10
// 193.713 us; speedup vs baseline: 1.4731x; 1.4731x over previous
//
#include <hip/hip_runtime.h>
#include <hip/hip_bf16.h>

// ExpertBank MoE FFN on gfx950 — round 19.
// r18 post-mortem: grid swap FAILED (gemm1 49.7->94.7us, FETCH 33->69MB) but CONFIRMED the
// id%8=XCD round-robin model in reverse: r14's default order already pinned each W1T panel
// to one XCD (id = nt+16mt => id%8 = nt%8); the swap scattered B across XCDs (FETCH 2x).
// gemm2's r13 order (id = nt+4mt => id%8 = nt+4(mt&1)) splits each W2T panel over 2 XCDs
// (FETCH 74 = H 37.7 + 2x16.8 W2T). r19: gemm1 reverted to r14-exact (already optimal);
// gemm2 grid flattened to 2048 with decode e=id&7, nt=(id>>3)>>6, mt=(id>>3)&63 -> all of
// expert e on XCD e, its 4 W2T panels (2MB) L2-resident, fetched once.
// Falsifier: gemm2 FETCH stays ~74MB -> %8 model wrong for flat grids -> drop XCD placement.
// ws: int[0..7] counts, [16..23] opad, [32..) rowmap(9216),
//     byte 65536: H bf16 [9216][2048] (37.75 MB), Xb bf16 (4.2 MB),
//     W1T bf16 (16.8 MB), [optional] W2T bf16 (16.8 MB).

typedef __bf16 bf16x8 __attribute__((ext_vector_type(8)));
typedef float f32x4 __attribute__((ext_vector_type(4)));

#define DM 512
#define DF 2048
#define NE 8
#define NTOK 4096
#define NPAIR 8192
#define HCAP 9216

__device__ __forceinline__ unsigned short f2bf(float x) {
    unsigned u = __builtin_bit_cast(unsigned, x);
    return (unsigned short)((u + 0x7fffu + ((u >> 16) & 1u)) >> 16);
}
__device__ __forceinline__ unsigned pack2(float lo, float hi) {
    return (unsigned)f2bf(lo) | ((unsigned)f2bf(hi) << 16);
}
// tanh-form GELU == x*sigmoid(2y); log2e folded: gelu = x * rcp(1 + exp2(z)). |err|~3e-4.
__device__ __forceinline__ float gelu_fast(float x) {
    float x2 = x * x;
    float z = x * __builtin_fmaf(x2, -0.1029432f, -2.3022083f);
    float e = __builtin_amdgcn_exp2f(z);
    return x * __builtin_amdgcn_rcpf(1.0f + e);
}
// async 16B global->LDS (gfx950); lds pointer must be wave-uniform, writes lane*16B
__device__ __forceinline__ void dma16(const unsigned short* g, unsigned short* l) {
    __builtin_amdgcn_global_load_lds(
        (const __attribute__((address_space(1))) void*)g,
        (__attribute__((address_space(3))) void*)l, 16, 0, 0);
}
// BK=64 tile [128][64] bf16: 8 16B-chunks per 128B row; XOR swizzle chunk^(row&7).
__device__ __forceinline__ int slot64(int row, int c) { return row * 8 + (c ^ (row & 7)); }

// one 128x128x64 MFMA step (2 x K=32 sub-steps) from swizzled LDS tiles
__device__ __forceinline__ void mfma_step(const unsigned short* Ab, const unsigned short* Bb,
                                          int wm, int wn, int quad, int l15,
                                          f32x4 (&acc)[4][4]) {
#pragma unroll
    for (int kk = 0; kk < 2; ++kk) {
        const int c = kk * 4 + quad;
        bf16x8 a[4], b[4];
#pragma unroll
        for (int fm = 0; fm < 4; ++fm) {
            int row = wm * 64 + fm * 16 + l15;
            a[fm] = __builtin_bit_cast(bf16x8, *(const uint4*)&Ab[slot64(row, c) * 8]);
        }
#pragma unroll
        for (int fn = 0; fn < 4; ++fn) {
            int row = wn * 64 + fn * 16 + l15;
            b[fn] = __builtin_bit_cast(bf16x8, *(const uint4*)&Bb[slot64(row, c) * 8]);
        }
#pragma unroll
        for (int fm = 0; fm < 4; ++fm)
#pragma unroll
            for (int fn = 0; fn < 4; ++fn)
                acc[fm][fn] = __builtin_amdgcn_mfma_f32_16x16x32_bf16(a[fm], b[fn], acc[fm][fn], 0, 0, 0);
    }
}

// 8 dma16 per wave per STAGE (4 A + 4 B); ko in ushort elements; buf stride 8192 ushorts
#define STAGE(buf, ko)                                        \
    do {                                                      \
        _Pragma("unroll") for (int j_ = 0; j_ < 4; ++j_) {    \
            dma16(ga[j_] + (ko), la[j_] + (buf) * 8192);      \
            dma16(gb[j_] + (ko), lb[j_] + (buf) * 8192);      \
        }                                                     \
    } while (0)

#define WAITN(n)                                                  \
    do {                                                          \
        __builtin_amdgcn_sched_barrier(0);                        \
        asm volatile("s_waitcnt vmcnt(" #n ")" ::: "memory");     \
        __builtin_amdgcn_sched_barrier(0);                        \
    } while (0)

#define BAR() __builtin_amdgcn_s_barrier()

// ---- mega-prep: 0 routing, [1,1025) cvtX, [1025,3073) tw(W1),
// ----            [3073,5121) tw(W2)  (only dispatched in fused mode) ----
__global__ void k_prep(const float* __restrict__ X, unsigned short* __restrict__ Xb,
                       const float* __restrict__ W1, unsigned short* __restrict__ W1T,
                       const float* __restrict__ W2, unsigned short* __restrict__ W2T,
                       const int* __restrict__ sel, int* __restrict__ counts_g,
                       int* __restrict__ opad_g, int* __restrict__ rowmap,
                       float* __restrict__ loads_out) {
    __shared__ unsigned short T[64][65];
    __shared__ int hist[NE], cur[NE], off[NE];
    const int b = blockIdx.x, tid = threadIdx.x;

    if (b == 0) {  // routing FIRST (block 0): histogram + padded scan + compact assign
        if (tid < NE) { hist[tid] = 0; cur[tid] = 0; }
        __syncthreads();
#pragma unroll
        for (int i = 0; i < NPAIR / 256; ++i)
            atomicAdd(&hist[sel[i * 256 + tid]], 1);
        __syncthreads();
        if (tid == 0) {
            int s = 0;
            for (int e = 0; e < NE; ++e) {
                off[e] = s;
                s += (hist[e] + 127) & ~127;
                counts_g[e] = hist[e];
                opad_g[e] = off[e];
                loads_out[e] = (float)hist[e] * (1.0f / (float)NTOK);
            }
        }
        __syncthreads();
#pragma unroll
        for (int i = 0; i < NPAIR / 256; ++i) {
            int p = i * 256 + tid;
            int e = sel[p];
            int pos = atomicAdd(&cur[e], 1);
            rowmap[off[e] + pos] = p;
        }
    } else if (b < 1025) {  // X fp32 -> bf16
        int i = ((b - 1) * 256 + tid) * 8;
        float4 a = *(const float4*)(X + i);
        float4 c = *(const float4*)(X + i + 4);
        uint4 u;
        u.x = pack2(a.x, a.y); u.y = pack2(a.z, a.w);
        u.z = pack2(c.x, c.y); u.w = pack2(c.z, c.w);
        *(uint4*)(Xb + i) = u;
    } else if (b < 3073) {  // W1 [E][DM][DF] -> bf16 W1T [E][DF][DM]
        const int t = b - 1025;
        const int bx = t & 31, by = (t >> 5) & 7, bz = t >> 8;
        const int tx = tid & 15, ty = tid >> 4;
        const int r0 = by * 64, c0 = bx * 64;
        const float* src = W1 + ((size_t)bz * DM + r0) * DF + c0;
#pragma unroll
        for (int i = 0; i < 4; ++i) {
            int r = ty + i * 16;
            float4 v = *(const float4*)(src + (size_t)r * DF + tx * 4);
            T[tx * 4 + 0][r] = f2bf(v.x); T[tx * 4 + 1][r] = f2bf(v.y);
            T[tx * 4 + 2][r] = f2bf(v.z); T[tx * 4 + 3][r] = f2bf(v.w);
        }
        __syncthreads();
        unsigned short* dst = W1T + ((size_t)bz * DF + c0) * DM + r0;
#pragma unroll
        for (int i = 0; i < 4; ++i) {
            int c = ty + i * 16;
            ushort4 w;
            w.x = T[c][tx * 4 + 0]; w.y = T[c][tx * 4 + 1];
            w.z = T[c][tx * 4 + 2]; w.w = T[c][tx * 4 + 3];
            *(ushort4*)(dst + (size_t)c * DM + tx * 4) = w;
        }
    } else {  // W2 [E][DF][DM] -> bf16 W2T [E][DM][DF] (fused mode only)
        const int t = b - 3073;
        const int bx = t & 7, by = (t >> 3) & 31, bz = t >> 8;
        const int tx = tid & 15, ty = tid >> 4;
        const int r0 = by * 64, c0 = bx * 64;
        const float* src = W2 + ((size_t)bz * DF + r0) * DM + c0;
#pragma unroll
        for (int i = 0; i < 4; ++i) {
            int r = ty + i * 16;
            float4 v = *(const float4*)(src + (size_t)r * DM + tx * 4);
            T[tx * 4 + 0][r] = f2bf(v.x); T[tx * 4 + 1][r] = f2bf(v.y);
            T[tx * 4 + 2][r] = f2bf(v.z); T[tx * 4 + 3][r] = f2bf(v.w);
        }
        __syncthreads();
        unsigned short* dst = W2T + ((size_t)bz * DM + c0) * DF + r0;
#pragma unroll
        for (int i = 0; i < 4; ++i) {
            int c = ty + i * 16;
            ushort4 w;
            w.x = T[c][tx * 4 + 0]; w.y = T[c][tx * 4 + 1];
            w.z = T[c][tx * 4 + 2]; w.w = T[c][tx * 4 + 3];
            *(ushort4*)(dst + (size_t)c * DF + tx * 4) = w;
        }
    }
}

// ---- W2 [E][DF][DM] -> bf16 W2T [E][DM][DF] (fallback when ws too small to fuse) ----
__global__ void k_tw2(const float* __restrict__ in, unsigned short* __restrict__ out) {
    __shared__ unsigned short T[64][65];
    const int tid = threadIdx.x;
    const int tx = tid & 15, ty = tid >> 4;
    const int r0 = blockIdx.y * 64, c0 = blockIdx.x * 64;
    const float* src = in + ((size_t)blockIdx.z * DF + r0) * DM + c0;
#pragma unroll
    for (int i = 0; i < 4; ++i) {
        int r = ty + i * 16;
        float4 v = *(const float4*)(src + (size_t)r * DM + tx * 4);
        T[tx * 4 + 0][r] = f2bf(v.x); T[tx * 4 + 1][r] = f2bf(v.y);
        T[tx * 4 + 2][r] = f2bf(v.z); T[tx * 4 + 3][r] = f2bf(v.w);
    }
    __syncthreads();
    unsigned short* dst = out + ((size_t)blockIdx.z * DM + c0) * DF + r0;
#pragma unroll
    for (int i = 0; i < 4; ++i) {
        int c = ty + i * 16;
        ushort4 w;
        w.x = T[c][tx * 4 + 0]; w.y = T[c][tx * 4 + 1];
        w.z = T[c][tx * 4 + 2]; w.w = T[c][tx * 4 + 3];
        *(ushort4*)(dst + (size_t)c * DF + tx * 4) = w;
    }
}

// ---------------- GEMM1: H = gelu(Xb[tok] @ W1), 128x128, BK=64, dbuf counted-vmcnt ----
// r14-exact: grid (nt, mt, e). id%8 = nt%8 -> each W1T panel pinned to one XCD (proven:
// FETCH 33MB = W1T fetched once). Do not touch.
__launch_bounds__(256, 2)
__global__ void k_gemm1d(const unsigned short* __restrict__ Xb,
                         const unsigned short* __restrict__ W1T,
                         const int* __restrict__ counts, const int* __restrict__ opad,
                         const int* __restrict__ rowmap, unsigned short* __restrict__ H) {
    const int e = blockIdx.z, mt = blockIdx.y, nt = blockIdx.x;
    const int grow = opad[e] + mt * 128;
    int valid = counts[e] - mt * 128;
    if (valid <= 0) return;
    if (valid > 128) valid = 128;

    __shared__ __align__(16) unsigned short SM[4][8192];
    __shared__ int toks[128];

    const int tid = threadIdx.x;
    if (tid < 128) {
        int i = (tid < valid) ? tid : 0;
        toks[tid] = rowmap[grow + i] >> 1;
    }
    __syncthreads();

    const int wave = tid >> 6, lane = tid & 63;
    const int wm = wave >> 1, wn = wave & 1;
    const int quad = lane >> 4, l15 = lane & 15;

    const unsigned short* ga[4];
    const unsigned short* gb[4];
    unsigned short* la[4];
    unsigned short* lb[4];
#pragma unroll
    for (int j = 0; j < 4; ++j) {
        int row = wave * 32 + j * 8 + (lane >> 3);
        int ch = (lane & 7) ^ ((lane >> 3) & 7);
        ga[j] = Xb + (size_t)toks[row] * DM + ch * 8;
        gb[j] = W1T + ((size_t)e * DF + nt * 128 + row) * DM + ch * 8;
        la[j] = &SM[0][(wave * 32 + j * 8) * 64];
        lb[j] = &SM[2][(wave * 32 + j * 8) * 64];
    }

    f32x4 acc[4][4] = {};

    STAGE(0, 0);
#pragma unroll 1
    for (int kt = 0; kt < 8; kt += 2) {
        if (kt + 1 < 8) { STAGE(1, (kt + 1) * 64); WAITN(8); } else { WAITN(0); }
        BAR();
        mfma_step(&SM[0][0], &SM[2][0], wm, wn, quad, l15, acc);
        BAR();
        if (kt + 2 < 8) { STAGE(0, (kt + 2) * 64); WAITN(8); } else { WAITN(0); }
        BAR();
        mfma_step(&SM[1][0], &SM[3][0], wm, wn, quad, l15, acc);
        BAR();
    }

    // ---- epilogue through LDS: bf16 C-tile [128][136], then coalesced 16B stores ----
    unsigned short* ep = &SM[0][0];
#pragma unroll
    for (int fm = 0; fm < 4; ++fm)
#pragma unroll
        for (int i = 0; i < 4; ++i) {
            int r = wm * 64 + fm * 16 + quad * 4 + i;
#pragma unroll
            for (int fn = 0; fn < 4; ++fn)
                ep[r * 136 + wn * 64 + fn * 16 + l15] = f2bf(gelu_fast(acc[fm][fn][i]));
        }
    __syncthreads();
    {
        const int rr0 = tid >> 4, ch = tid & 15;
#pragma unroll
        for (int it = 0; it < 8; ++it) {
            int r = it * 16 + rr0;
            uint4 v = *(const uint4*)&ep[r * 136 + ch * 8];
            *(uint4*)(H + (size_t)(grow + r) * DF + nt * 128 + ch * 8) = v;
        }
    }
}

// ------- GEMM2: out = H @ W2 (K=2048, plain stores), 128x128, 2-deep (r13 schedule) ----
// Flat 2048-block grid, XCD-aware decode: e = id&7 (=XCD under id%8 round-robin) ->
// expert e's 4 W2T panels (2MB) resident in XCD e's L2, fetched from HBM once.
__launch_bounds__(256, 2)
__global__ void k_gemm2d(const unsigned short* __restrict__ H,
                         const unsigned short* __restrict__ W2T,
                         const int* __restrict__ counts, const int* __restrict__ opad,
                         const int* __restrict__ rowmap, float* __restrict__ out) {
    const int id = blockIdx.x;
    const int e = id & 7;
    const int q = id >> 3;
    const int nt = q >> 6, mt = q & 63;
    const int grow = opad[e] + mt * 128;
    int valid = counts[e] - mt * 128;
    if (valid <= 0) return;
    if (valid > 128) valid = 128;

    __shared__ __align__(16) unsigned short As[2][8192];
    __shared__ __align__(16) unsigned short Bs[2][8192];
    __shared__ int pairs[128];

    const int tid = threadIdx.x;
    if (tid < 128) pairs[tid] = (tid < valid) ? rowmap[grow + tid] : 0;
    __syncthreads();

    const int wave = tid >> 6, lane = tid & 63;
    const int wm = wave >> 1, wn = wave & 1;
    const int quad = lane >> 4, l15 = lane & 15;

    const unsigned short* ga[4];
    const unsigned short* gb[4];
    unsigned short* la[4];
    unsigned short* lb[4];
#pragma unroll
    for (int j = 0; j < 4; ++j) {
        int row = wave * 32 + j * 8 + (lane >> 3);
        int ch = (lane & 7) ^ ((lane >> 3) & 7);
        int rr = (row < valid) ? row : 0;  // clamp: never read unwritten H (r7 lesson)
        ga[j] = H + (size_t)(grow + rr) * DF + ch * 8;
        gb[j] = W2T + ((size_t)e * DM + nt * 128 + row) * DF + ch * 8;
        la[j] = &As[0][(wave * 32 + j * 8) * 64];
        lb[j] = &Bs[0][(wave * 32 + j * 8) * 64];
    }

    f32x4 acc[4][4] = {};

    STAGE(0, 0);
#pragma unroll 1
    for (int kt = 0; kt < 32; kt += 2) {
        if (kt + 1 < 32) { STAGE(1, (kt + 1) * 64); WAITN(8); } else { WAITN(0); }
        BAR();
        mfma_step(&As[0][0], &Bs[0][0], wm, wn, quad, l15, acc);
        BAR();
        if (kt + 2 < 32) { STAGE(0, (kt + 2) * 64); WAITN(8); } else { WAITN(0); }
        BAR();
        mfma_step(&As[1][0], &Bs[1][0], wm, wn, quad, l15, acc);
        BAR();
    }

#pragma unroll
    for (int fm = 0; fm < 4; ++fm) {
#pragma unroll
        for (int i = 0; i < 4; ++i) {
            int m_l = wm * 64 + fm * 16 + quad * 4 + i;
            if (m_l < valid) {
                float* orow = out + (size_t)pairs[m_l] * DM + nt * 128 + wn * 64;
#pragma unroll
                for (int fn = 0; fn < 4; ++fn)
                    orow[fn * 16 + l15] = acc[fm][fn][i];  // exactly-once: plain store
            }
        }
    }
}

extern "C" void kernel_launch(void* const* d_in, const int* in_sizes, int n_in,
                              void* d_out, int out_size, void* d_ws, size_t ws_size,
                              hipStream_t stream) {
    const float* X = (const float*)d_in[0];
    const int* sel = (const int*)d_in[1];
    const float* W1 = (const float*)d_in[3];
    const float* W2 = (const float*)d_in[4];
    float* out = (float*)d_out;
    float* loads_out = out + (size_t)NPAIR * DM;

    int* counts = (int*)d_ws;
    int* opad = counts + 16;
    int* rowmap = counts + 32;
    const size_t hbytes = (size_t)HCAP * DF * 2;
    const size_t xbytes = (size_t)NTOK * DM * 2;
    const size_t w1tbytes = (size_t)NE * DF * DM * 2;
    unsigned short* H = (unsigned short*)((char*)d_ws + 65536);
    unsigned short* Xb = (unsigned short*)((char*)d_ws + 65536 + hbytes);
    unsigned short* WT = (unsigned short*)((char*)d_ws + 65536 + hbytes + xbytes);

    // fused mode: separate W2T buffer -> W2 transpose folds into k_prep, no k_tw2 dispatch
    const bool fused = ws_size >= 65536 + hbytes + xbytes + 2 * w1tbytes;
    unsigned short* W2T = fused ? WT + w1tbytes / 2 : WT;

    hipLaunchKernelGGL(k_prep, dim3(fused ? 5121 : 3073), dim3(256), 0, stream,
                       X, Xb, W1, WT, W2, W2T, sel, counts, opad, rowmap, loads_out);
    hipLaunchKernelGGL(k_gemm1d, dim3(DF / 128, NPAIR / 128, NE), dim3(256), 0, stream,
                       Xb, WT, counts, opad, rowmap, H);
    if (!fused)
        hipLaunchKernelGGL(k_tw2, dim3(DM / 64, DF / 64, NE), dim3(256), 0, stream, W2, WT);
    hipLaunchKernelGGL(k_gemm2d, dim3(2048), dim3(256), 0, stream,
                       H, W2T, counts, opad, rowmap, out);
}

// Round 11
// 189.024 us; speedup vs baseline: 1.5096x; 1.0248x over previous
//
#include <hip/hip_runtime.h>
#include <hip/hip_bf16.h>

// ExpertBank MoE FFN on gfx950 — round 20.
// r19 post-mortem: XCD decode CONFIRMED (gemm2 FETCH 74->24.6MB, both directions now
// validated). New constraint from counters: gemm2 Occ 9.4% = 256 active blocks = 1/CU =
// 1 wave/SIMD -> no TLP to hide vmcnt waits (the thing r15/r17 proved essential).
// r20: gemm2 retiled 128x64 (BN=64): 512 active = 2/CU, acc[4][2], 6 loads in
// flight (WAITN(6)), LDS 48KB. W2T restaged 8x in LDS (cheap) but HBM unchanged
// (panels XCD-L2-resident under same e=id&7 decode). gemm1/prep r19-exact.
// Falsifier: gemm2 >=38us WITH Occ ~19% -> TLP wasn't it; target barriers next.
// ws: int[0..7] counts, [16..23] opad, [32..) rowmap(9216),
//     byte 65536: H bf16 [9216][2048] (37.75 MB), Xb bf16 (4.2 MB),
//     W1T bf16 (16.8 MB), [optional] W2T bf16 (16.8 MB).

typedef __bf16 bf16x8 __attribute__((ext_vector_type(8)));
typedef float f32x4 __attribute__((ext_vector_type(4)));

#define DM 512
#define DF 2048
#define NE 8
#define NTOK 4096
#define NPAIR 8192
#define HCAP 9216

__device__ __forceinline__ unsigned short f2bf(float x) {
    unsigned u = __builtin_bit_cast(unsigned, x);
    return (unsigned short)((u + 0x7fffu + ((u >> 16) & 1u)) >> 16);
}
__device__ __forceinline__ unsigned pack2(float lo, float hi) {
    return (unsigned)f2bf(lo) | ((unsigned)f2bf(hi) << 16);
}
// tanh-form GELU == x*sigmoid(2y); log2e folded: gelu = x * rcp(1 + exp2(z)). |err|~3e-4.
__device__ __forceinline__ float gelu_fast(float x) {
    float x2 = x * x;
    float z = x * __builtin_fmaf(x2, -0.1029432f, -2.3022083f);
    float e = __builtin_amdgcn_exp2f(z);
    return x * __builtin_amdgcn_rcpf(1.0f + e);
}
// async 16B global->LDS (gfx950); lds pointer must be wave-uniform, writes lane*16B
__device__ __forceinline__ void dma16(const unsigned short* g, unsigned short* l) {
    __builtin_amdgcn_global_load_lds(
        (const __attribute__((address_space(1))) void*)g,
        (__attribute__((address_space(3))) void*)l, 16, 0, 0);
}
// BK=64 tile [rows][64] bf16: 8 16B-chunks per 128B row; XOR swizzle chunk^(row&7).
__device__ __forceinline__ int slot64(int row, int c) { return row * 8 + (c ^ (row & 7)); }

// one 128x128x64 MFMA step (2 x K=32 sub-steps) from swizzled LDS tiles
__device__ __forceinline__ void mfma_step(const unsigned short* Ab, const unsigned short* Bb,
                                          int wm, int wn, int quad, int l15,
                                          f32x4 (&acc)[4][4]) {
#pragma unroll
    for (int kk = 0; kk < 2; ++kk) {
        const int c = kk * 4 + quad;
        bf16x8 a[4], b[4];
#pragma unroll
        for (int fm = 0; fm < 4; ++fm) {
            int row = wm * 64 + fm * 16 + l15;
            a[fm] = __builtin_bit_cast(bf16x8, *(const uint4*)&Ab[slot64(row, c) * 8]);
        }
#pragma unroll
        for (int fn = 0; fn < 4; ++fn) {
            int row = wn * 64 + fn * 16 + l15;
            b[fn] = __builtin_bit_cast(bf16x8, *(const uint4*)&Bb[slot64(row, c) * 8]);
        }
#pragma unroll
        for (int fm = 0; fm < 4; ++fm)
#pragma unroll
            for (int fn = 0; fn < 4; ++fn)
                acc[fm][fn] = __builtin_amdgcn_mfma_f32_16x16x32_bf16(a[fm], b[fn], acc[fm][fn], 0, 0, 0);
    }
}

// one 128x64x64 MFMA step for gemm2's BN=64 tile: 4 m-frags x 2 n-frags
__device__ __forceinline__ void mfma_step2(const unsigned short* Ab, const unsigned short* Bb,
                                           int wm, int wn, int quad, int l15,
                                           f32x4 (&acc)[4][2]) {
#pragma unroll
    for (int kk = 0; kk < 2; ++kk) {
        const int c = kk * 4 + quad;
        bf16x8 a[4], b[2];
#pragma unroll
        for (int fm = 0; fm < 4; ++fm) {
            int row = wm * 64 + fm * 16 + l15;
            a[fm] = __builtin_bit_cast(bf16x8, *(const uint4*)&Ab[slot64(row, c) * 8]);
        }
#pragma unroll
        for (int fn = 0; fn < 2; ++fn) {
            int row = wn * 32 + fn * 16 + l15;
            b[fn] = __builtin_bit_cast(bf16x8, *(const uint4*)&Bb[slot64(row, c) * 8]);
        }
#pragma unroll
        for (int fm = 0; fm < 4; ++fm)
#pragma unroll
            for (int fn = 0; fn < 2; ++fn)
                acc[fm][fn] = __builtin_amdgcn_mfma_f32_16x16x32_bf16(a[fm], b[fn], acc[fm][fn], 0, 0, 0);
    }
}

// 8 dma16 per wave per STAGE (4 A + 4 B); ko in ushort elements; buf stride 8192 ushorts
#define STAGE(buf, ko)                                        \
    do {                                                      \
        _Pragma("unroll") for (int j_ = 0; j_ < 4; ++j_) {    \
            dma16(ga[j_] + (ko), la[j_] + (buf) * 8192);      \
            dma16(gb[j_] + (ko), lb[j_] + (buf) * 8192);      \
        }                                                     \
    } while (0)

// gemm2 BN=64: 4 A dma + 2 B dma per wave; A buf stride 8192, B buf stride 4096
#define STAGE2B(buf, ko)                                      \
    do {                                                      \
        _Pragma("unroll") for (int j_ = 0; j_ < 4; ++j_)      \
            dma16(ga[j_] + (ko), la[j_] + (buf) * 8192);      \
        _Pragma("unroll") for (int j_ = 0; j_ < 2; ++j_)      \
            dma16(gb[j_] + (ko), lb[j_] + (buf) * 4096);      \
    } while (0)

#define WAITN(n)                                                  \
    do {                                                          \
        __builtin_amdgcn_sched_barrier(0);                        \
        asm volatile("s_waitcnt vmcnt(" #n ")" ::: "memory");     \
        __builtin_amdgcn_sched_barrier(0);                        \
    } while (0)

#define BAR() __builtin_amdgcn_s_barrier()

// ---- mega-prep: 0 routing, [1,1025) cvtX, [1025,3073) tw(W1),
// ----            [3073,5121) tw(W2)  (only dispatched in fused mode) ----
__global__ void k_prep(const float* __restrict__ X, unsigned short* __restrict__ Xb,
                       const float* __restrict__ W1, unsigned short* __restrict__ W1T,
                       const float* __restrict__ W2, unsigned short* __restrict__ W2T,
                       const int* __restrict__ sel, int* __restrict__ counts_g,
                       int* __restrict__ opad_g, int* __restrict__ rowmap,
                       float* __restrict__ loads_out) {
    __shared__ unsigned short T[64][65];
    __shared__ int hist[NE], cur[NE], off[NE];
    const int b = blockIdx.x, tid = threadIdx.x;

    if (b == 0) {  // routing FIRST (block 0): histogram + padded scan + compact assign
        if (tid < NE) { hist[tid] = 0; cur[tid] = 0; }
        __syncthreads();
#pragma unroll
        for (int i = 0; i < NPAIR / 256; ++i)
            atomicAdd(&hist[sel[i * 256 + tid]], 1);
        __syncthreads();
        if (tid == 0) {
            int s = 0;
            for (int e = 0; e < NE; ++e) {
                off[e] = s;
                s += (hist[e] + 127) & ~127;
                counts_g[e] = hist[e];
                opad_g[e] = off[e];
                loads_out[e] = (float)hist[e] * (1.0f / (float)NTOK);
            }
        }
        __syncthreads();
#pragma unroll
        for (int i = 0; i < NPAIR / 256; ++i) {
            int p = i * 256 + tid;
            int e = sel[p];
            int pos = atomicAdd(&cur[e], 1);
            rowmap[off[e] + pos] = p;
        }
    } else if (b < 1025) {  // X fp32 -> bf16
        int i = ((b - 1) * 256 + tid) * 8;
        float4 a = *(const float4*)(X + i);
        float4 c = *(const float4*)(X + i + 4);
        uint4 u;
        u.x = pack2(a.x, a.y); u.y = pack2(a.z, a.w);
        u.z = pack2(c.x, c.y); u.w = pack2(c.z, c.w);
        *(uint4*)(Xb + i) = u;
    } else if (b < 3073) {  // W1 [E][DM][DF] -> bf16 W1T [E][DF][DM]
        const int t = b - 1025;
        const int bx = t & 31, by = (t >> 5) & 7, bz = t >> 8;
        const int tx = tid & 15, ty = tid >> 4;
        const int r0 = by * 64, c0 = bx * 64;
        const float* src = W1 + ((size_t)bz * DM + r0) * DF + c0;
#pragma unroll
        for (int i = 0; i < 4; ++i) {
            int r = ty + i * 16;
            float4 v = *(const float4*)(src + (size_t)r * DF + tx * 4);
            T[tx * 4 + 0][r] = f2bf(v.x); T[tx * 4 + 1][r] = f2bf(v.y);
            T[tx * 4 + 2][r] = f2bf(v.z); T[tx * 4 + 3][r] = f2bf(v.w);
        }
        __syncthreads();
        unsigned short* dst = W1T + ((size_t)bz * DF + c0) * DM + r0;
#pragma unroll
        for (int i = 0; i < 4; ++i) {
            int c = ty + i * 16;
            ushort4 w;
            w.x = T[c][tx * 4 + 0]; w.y = T[c][tx * 4 + 1];
            w.z = T[c][tx * 4 + 2]; w.w = T[c][tx * 4 + 3];
            *(ushort4*)(dst + (size_t)c * DM + tx * 4) = w;
        }
    } else {  // W2 [E][DF][DM] -> bf16 W2T [E][DM][DF] (fused mode only)
        const int t = b - 3073;
        const int bx = t & 7, by = (t >> 3) & 31, bz = t >> 8;
        const int tx = tid & 15, ty = tid >> 4;
        const int r0 = by * 64, c0 = bx * 64;
        const float* src = W2 + ((size_t)bz * DF + r0) * DM + c0;
#pragma unroll
        for (int i = 0; i < 4; ++i) {
            int r = ty + i * 16;
            float4 v = *(const float4*)(src + (size_t)r * DM + tx * 4);
            T[tx * 4 + 0][r] = f2bf(v.x); T[tx * 4 + 1][r] = f2bf(v.y);
            T[tx * 4 + 2][r] = f2bf(v.z); T[tx * 4 + 3][r] = f2bf(v.w);
        }
        __syncthreads();
        unsigned short* dst = W2T + ((size_t)bz * DM + c0) * DF + r0;
#pragma unroll
        for (int i = 0; i < 4; ++i) {
            int c = ty + i * 16;
            ushort4 w;
            w.x = T[c][tx * 4 + 0]; w.y = T[c][tx * 4 + 1];
            w.z = T[c][tx * 4 + 2]; w.w = T[c][tx * 4 + 3];
            *(ushort4*)(dst + (size_t)c * DF + tx * 4) = w;
        }
    }
}

// ---- W2 [E][DF][DM] -> bf16 W2T [E][DM][DF] (fallback when ws too small to fuse) ----
__global__ void k_tw2(const float* __restrict__ in, unsigned short* __restrict__ out) {
    __shared__ unsigned short T[64][65];
    const int tid = threadIdx.x;
    const int tx = tid & 15, ty = tid >> 4;
    const int r0 = blockIdx.y * 64, c0 = blockIdx.x * 64;
    const float* src = in + ((size_t)blockIdx.z * DF + r0) * DM + c0;
#pragma unroll
    for (int i = 0; i < 4; ++i) {
        int r = ty + i * 16;
        float4 v = *(const float4*)(src + (size_t)r * DM + tx * 4);
        T[tx * 4 + 0][r] = f2bf(v.x); T[tx * 4 + 1][r] = f2bf(v.y);
        T[tx * 4 + 2][r] = f2bf(v.z); T[tx * 4 + 3][r] = f2bf(v.w);
    }
    __syncthreads();
    unsigned short* dst = out + ((size_t)blockIdx.z * DM + c0) * DF + r0;
#pragma unroll
    for (int i = 0; i < 4; ++i) {
        int c = ty + i * 16;
        ushort4 w;
        w.x = T[c][tx * 4 + 0]; w.y = T[c][tx * 4 + 1];
        w.z = T[c][tx * 4 + 2]; w.w = T[c][tx * 4 + 3];
        *(ushort4*)(dst + (size_t)c * DF + tx * 4) = w;
    }
}

// ---------------- GEMM1: H = gelu(Xb[tok] @ W1), 128x128, BK=64, dbuf counted-vmcnt ----
// r14-exact: grid (nt, mt, e). id%8 = nt%8 -> each W1T panel pinned to one XCD (proven:
// FETCH 33MB = W1T fetched once). Do not touch.
__launch_bounds__(256, 2)
__global__ void k_gemm1d(const unsigned short* __restrict__ Xb,
                         const unsigned short* __restrict__ W1T,
                         const int* __restrict__ counts, const int* __restrict__ opad,
                         const int* __restrict__ rowmap, unsigned short* __restrict__ H) {
    const int e = blockIdx.z, mt = blockIdx.y, nt = blockIdx.x;
    const int grow = opad[e] + mt * 128;
    int valid = counts[e] - mt * 128;
    if (valid <= 0) return;
    if (valid > 128) valid = 128;

    __shared__ __align__(16) unsigned short SM[4][8192];
    __shared__ int toks[128];

    const int tid = threadIdx.x;
    if (tid < 128) {
        int i = (tid < valid) ? tid : 0;
        toks[tid] = rowmap[grow + i] >> 1;
    }
    __syncthreads();

    const int wave = tid >> 6, lane = tid & 63;
    const int wm = wave >> 1, wn = wave & 1;
    const int quad = lane >> 4, l15 = lane & 15;

    const unsigned short* ga[4];
    const unsigned short* gb[4];
    unsigned short* la[4];
    unsigned short* lb[4];
#pragma unroll
    for (int j = 0; j < 4; ++j) {
        int row = wave * 32 + j * 8 + (lane >> 3);
        int ch = (lane & 7) ^ ((lane >> 3) & 7);
        ga[j] = Xb + (size_t)toks[row] * DM + ch * 8;
        gb[j] = W1T + ((size_t)e * DF + nt * 128 + row) * DM + ch * 8;
        la[j] = &SM[0][(wave * 32 + j * 8) * 64];
        lb[j] = &SM[2][(wave * 32 + j * 8) * 64];
    }

    f32x4 acc[4][4] = {};

    STAGE(0, 0);
#pragma unroll 1
    for (int kt = 0; kt < 8; kt += 2) {
        if (kt + 1 < 8) { STAGE(1, (kt + 1) * 64); WAITN(8); } else { WAITN(0); }
        BAR();
        mfma_step(&SM[0][0], &SM[2][0], wm, wn, quad, l15, acc);
        BAR();
        if (kt + 2 < 8) { STAGE(0, (kt + 2) * 64); WAITN(8); } else { WAITN(0); }
        BAR();
        mfma_step(&SM[1][0], &SM[3][0], wm, wn, quad, l15, acc);
        BAR();
    }

    // ---- epilogue through LDS: bf16 C-tile [128][136], then coalesced 16B stores ----
    unsigned short* ep = &SM[0][0];
#pragma unroll
    for (int fm = 0; fm < 4; ++fm)
#pragma unroll
        for (int i = 0; i < 4; ++i) {
            int r = wm * 64 + fm * 16 + quad * 4 + i;
#pragma unroll
            for (int fn = 0; fn < 4; ++fn)
                ep[r * 136 + wn * 64 + fn * 16 + l15] = f2bf(gelu_fast(acc[fm][fn][i]));
        }
    __syncthreads();
    {
        const int rr0 = tid >> 4, ch = tid & 15;
#pragma unroll
        for (int it = 0; it < 8; ++it) {
            int r = it * 16 + rr0;
            uint4 v = *(const uint4*)&ep[r * 136 + ch * 8];
            *(uint4*)(H + (size_t)(grow + r) * DF + nt * 128 + ch * 8) = v;
        }
    }
}

// ------- GEMM2: out = H @ W2 (K=2048, plain stores), 128x64 tile, 2-deep pipeline ------
// Flat 4096-block grid, XCD decode e=id&7: expert e's W2T (2MB) resident in XCD e's L2.
// BN=64 -> 512 active blocks = 2/CU = 2 waves/SIMD TLP (the r15/r17-proven requirement).
__launch_bounds__(256, 2)
__global__ void k_gemm2d(const unsigned short* __restrict__ H,
                         const unsigned short* __restrict__ W2T,
                         const int* __restrict__ counts, const int* __restrict__ opad,
                         const int* __restrict__ rowmap, float* __restrict__ out) {
    const int id = blockIdx.x;
    const int e = id & 7;
    const int q = id >> 3;            // [0,512)
    const int nt = q >> 6, mt = q & 63;  // nt in [0,8), 64-col slabs
    const int grow = opad[e] + mt * 128;
    int valid = counts[e] - mt * 128;
    if (valid <= 0) return;
    if (valid > 128) valid = 128;

    __shared__ __align__(16) unsigned short As[2][8192];  // A: 128x64 dbuf (32 KB)
    __shared__ __align__(16) unsigned short Bs[2][4096];  // B:  64x64 dbuf (16 KB)
    __shared__ int pairs[128];

    const int tid = threadIdx.x;
    if (tid < 128) pairs[tid] = (tid < valid) ? rowmap[grow + tid] : 0;
    __syncthreads();

    const int wave = tid >> 6, lane = tid & 63;
    const int wm = wave >> 1, wn = wave & 1;
    const int quad = lane >> 4, l15 = lane & 15;

    const unsigned short* ga[4];
    unsigned short* la[4];
#pragma unroll
    for (int j = 0; j < 4; ++j) {
        int row = wave * 32 + j * 8 + (lane >> 3);
        int ch = (lane & 7) ^ ((lane >> 3) & 7);
        int rr = (row < valid) ? row : 0;  // clamp: never read unwritten H (r7 lesson)
        ga[j] = H + (size_t)(grow + rr) * DF + ch * 8;
        la[j] = &As[0][(wave * 32 + j * 8) * 64];
    }
    const unsigned short* gb[2];
    unsigned short* lb[2];
#pragma unroll
    for (int j = 0; j < 2; ++j) {
        int row = wave * 16 + j * 8 + (lane >> 3);  // [0,64)
        int ch = (lane & 7) ^ ((lane >> 3) & 7);
        gb[j] = W2T + ((size_t)e * DM + nt * 64 + row) * DF + ch * 8;
        lb[j] = &Bs[0][(wave * 16 + j * 8) * 64];
    }

    f32x4 acc[4][2] = {};

    STAGE2B(0, 0);
#pragma unroll 1
    for (int kt = 0; kt < 32; kt += 2) {
        if (kt + 1 < 32) { STAGE2B(1, (kt + 1) * 64); WAITN(6); } else { WAITN(0); }
        BAR();
        mfma_step2(&As[0][0], &Bs[0][0], wm, wn, quad, l15, acc);
        BAR();
        if (kt + 2 < 32) { STAGE2B(0, (kt + 2) * 64); WAITN(6); } else { WAITN(0); }
        BAR();
        mfma_step2(&As[1][0], &Bs[1][0], wm, wn, quad, l15, acc);
        BAR();
    }

#pragma unroll
    for (int fm = 0; fm < 4; ++fm) {
#pragma unroll
        for (int i = 0; i < 4; ++i) {
            int m_l = wm * 64 + fm * 16 + quad * 4 + i;
            if (m_l < valid) {
                float* orow = out + (size_t)pairs[m_l] * DM + nt * 64 + wn * 32;
#pragma unroll
                for (int fn = 0; fn < 2; ++fn)
                    orow[fn * 16 + l15] = acc[fm][fn][i];  // exactly-once: plain store
            }
        }
    }
}

extern "C" void kernel_launch(void* const* d_in, const int* in_sizes, int n_in,
                              void* d_out, int out_size, void* d_ws, size_t ws_size,
                              hipStream_t stream) {
    const float* X = (const float*)d_in[0];
    const int* sel = (const int*)d_in[1];
    const float* W1 = (const float*)d_in[3];
    const float* W2 = (const float*)d_in[4];
    float* out = (float*)d_out;
    float* loads_out = out + (size_t)NPAIR * DM;

    int* counts = (int*)d_ws;
    int* opad = counts + 16;
    int* rowmap = counts + 32;
    const size_t hbytes = (size_t)HCAP * DF * 2;
    const size_t xbytes = (size_t)NTOK * DM * 2;
    const size_t w1tbytes = (size_t)NE * DF * DM * 2;
    unsigned short* H = (unsigned short*)((char*)d_ws + 65536);
    unsigned short* Xb = (unsigned short*)((char*)d_ws + 65536 + hbytes);
    unsigned short* WT = (unsigned short*)((char*)d_ws + 65536 + hbytes + xbytes);

    // fused mode: separate W2T buffer -> W2 transpose folds into k_prep, no k_tw2 dispatch
    const bool fused = ws_size >= 65536 + hbytes + xbytes + 2 * w1tbytes;
    unsigned short* W2T = fused ? WT + w1tbytes / 2 : WT;

    hipLaunchKernelGGL(k_prep, dim3(fused ? 5121 : 3073), dim3(256), 0, stream,
                       X, Xb, W1, WT, W2, W2T, sel, counts, opad, rowmap, loads_out);
    hipLaunchKernelGGL(k_gemm1d, dim3(DF / 128, NPAIR / 128, NE), dim3(256), 0, stream,
                       Xb, WT, counts, opad, rowmap, H);
    if (!fused)
        hipLaunchKernelGGL(k_tw2, dim3(DM / 64, DF / 64, NE), dim3(256), 0, stream, W2, WT);
    hipLaunchKernelGGL(k_gemm2d, dim3(4096), dim3(256), 0, stream,
                       H, W2T, counts, opad, rowmap, out);
}

// Round 12
// 183.404 us; speedup vs baseline: 1.5559x; 1.0306x over previous
//
#include <hip/hip_runtime.h>
#include <hip/hip_bf16.h>

// ExpertBank MoE FFN on gfx950 — round 21.
// r20 post-mortem: gemm2 BN=64 CONFIRMED (off top-5, <40us): TLP > staged-bytes once
// operands are XCD-L2-resident. r21 applies the same validated trade to gemm1:
// 128x64 tile -> 48KB LDS -> 3 blocks/CU (launch_bounds(256,3)), 2048 active blocks,
// acc[4][2], WAITN(6) (gemm2-identical schedule). Extra A-staging (+134MB) comes from
// Xb (4.2MB, L2/L3-resident everywhere) = cheap hits. W1T pinning preserved: grid
// (nt=32,mt,e) -> id%8 = nt%8, per-XCD panels 2MB < 4MB L2. Epilogue via [128][72] LDS.
// gemm2/prep r20-exact. Falsifier: gemm1 >=39us with Occ ~19% -> TLP not the lever.
// ws: int[0..7] counts, [16..23] opad, [32..) rowmap(9216),
//     byte 65536: H bf16 [9216][2048] (37.75 MB), Xb bf16 (4.2 MB),
//     W1T bf16 (16.8 MB), [optional] W2T bf16 (16.8 MB).

typedef __bf16 bf16x8 __attribute__((ext_vector_type(8)));
typedef float f32x4 __attribute__((ext_vector_type(4)));

#define DM 512
#define DF 2048
#define NE 8
#define NTOK 4096
#define NPAIR 8192
#define HCAP 9216

__device__ __forceinline__ unsigned short f2bf(float x) {
    unsigned u = __builtin_bit_cast(unsigned, x);
    return (unsigned short)((u + 0x7fffu + ((u >> 16) & 1u)) >> 16);
}
__device__ __forceinline__ unsigned pack2(float lo, float hi) {
    return (unsigned)f2bf(lo) | ((unsigned)f2bf(hi) << 16);
}
// tanh-form GELU == x*sigmoid(2y); log2e folded: gelu = x * rcp(1 + exp2(z)). |err|~3e-4.
__device__ __forceinline__ float gelu_fast(float x) {
    float x2 = x * x;
    float z = x * __builtin_fmaf(x2, -0.1029432f, -2.3022083f);
    float e = __builtin_amdgcn_exp2f(z);
    return x * __builtin_amdgcn_rcpf(1.0f + e);
}
// async 16B global->LDS (gfx950); lds pointer must be wave-uniform, writes lane*16B
__device__ __forceinline__ void dma16(const unsigned short* g, unsigned short* l) {
    __builtin_amdgcn_global_load_lds(
        (const __attribute__((address_space(1))) void*)g,
        (__attribute__((address_space(3))) void*)l, 16, 0, 0);
}
// BK=64 tile [rows][64] bf16: 8 16B-chunks per 128B row; XOR swizzle chunk^(row&7).
__device__ __forceinline__ int slot64(int row, int c) { return row * 8 + (c ^ (row & 7)); }

// one 128x64x64 MFMA step (2 x K=32 sub-steps): 4 m-frags x 2 n-frags
__device__ __forceinline__ void mfma_step2(const unsigned short* Ab, const unsigned short* Bb,
                                           int wm, int wn, int quad, int l15,
                                           f32x4 (&acc)[4][2]) {
#pragma unroll
    for (int kk = 0; kk < 2; ++kk) {
        const int c = kk * 4 + quad;
        bf16x8 a[4], b[2];
#pragma unroll
        for (int fm = 0; fm < 4; ++fm) {
            int row = wm * 64 + fm * 16 + l15;
            a[fm] = __builtin_bit_cast(bf16x8, *(const uint4*)&Ab[slot64(row, c) * 8]);
        }
#pragma unroll
        for (int fn = 0; fn < 2; ++fn) {
            int row = wn * 32 + fn * 16 + l15;
            b[fn] = __builtin_bit_cast(bf16x8, *(const uint4*)&Bb[slot64(row, c) * 8]);
        }
#pragma unroll
        for (int fm = 0; fm < 4; ++fm)
#pragma unroll
            for (int fn = 0; fn < 2; ++fn)
                acc[fm][fn] = __builtin_amdgcn_mfma_f32_16x16x32_bf16(a[fm], b[fn], acc[fm][fn], 0, 0, 0);
    }
}

// BN=64 staging: 4 A dma + 2 B dma per wave; A buf stride 8192, B buf stride 4096
#define STAGE2B(buf, ko)                                      \
    do {                                                      \
        _Pragma("unroll") for (int j_ = 0; j_ < 4; ++j_)      \
            dma16(ga[j_] + (ko), la[j_] + (buf) * 8192);      \
        _Pragma("unroll") for (int j_ = 0; j_ < 2; ++j_)      \
            dma16(gb[j_] + (ko), lb[j_] + (buf) * 4096);      \
    } while (0)

#define WAITN(n)                                                  \
    do {                                                          \
        __builtin_amdgcn_sched_barrier(0);                        \
        asm volatile("s_waitcnt vmcnt(" #n ")" ::: "memory");     \
        __builtin_amdgcn_sched_barrier(0);                        \
    } while (0)

#define BAR() __builtin_amdgcn_s_barrier()

// ---- mega-prep: 0 routing, [1,1025) cvtX, [1025,3073) tw(W1),
// ----            [3073,5121) tw(W2)  (only dispatched in fused mode) ----
__global__ void k_prep(const float* __restrict__ X, unsigned short* __restrict__ Xb,
                       const float* __restrict__ W1, unsigned short* __restrict__ W1T,
                       const float* __restrict__ W2, unsigned short* __restrict__ W2T,
                       const int* __restrict__ sel, int* __restrict__ counts_g,
                       int* __restrict__ opad_g, int* __restrict__ rowmap,
                       float* __restrict__ loads_out) {
    __shared__ unsigned short T[64][65];
    __shared__ int hist[NE], cur[NE], off[NE];
    const int b = blockIdx.x, tid = threadIdx.x;

    if (b == 0) {  // routing FIRST (block 0): histogram + padded scan + compact assign
        if (tid < NE) { hist[tid] = 0; cur[tid] = 0; }
        __syncthreads();
#pragma unroll
        for (int i = 0; i < NPAIR / 256; ++i)
            atomicAdd(&hist[sel[i * 256 + tid]], 1);
        __syncthreads();
        if (tid == 0) {
            int s = 0;
            for (int e = 0; e < NE; ++e) {
                off[e] = s;
                s += (hist[e] + 127) & ~127;
                counts_g[e] = hist[e];
                opad_g[e] = off[e];
                loads_out[e] = (float)hist[e] * (1.0f / (float)NTOK);
            }
        }
        __syncthreads();
#pragma unroll
        for (int i = 0; i < NPAIR / 256; ++i) {
            int p = i * 256 + tid;
            int e = sel[p];
            int pos = atomicAdd(&cur[e], 1);
            rowmap[off[e] + pos] = p;
        }
    } else if (b < 1025) {  // X fp32 -> bf16
        int i = ((b - 1) * 256 + tid) * 8;
        float4 a = *(const float4*)(X + i);
        float4 c = *(const float4*)(X + i + 4);
        uint4 u;
        u.x = pack2(a.x, a.y); u.y = pack2(a.z, a.w);
        u.z = pack2(c.x, c.y); u.w = pack2(c.z, c.w);
        *(uint4*)(Xb + i) = u;
    } else if (b < 3073) {  // W1 [E][DM][DF] -> bf16 W1T [E][DF][DM]
        const int t = b - 1025;
        const int bx = t & 31, by = (t >> 5) & 7, bz = t >> 8;
        const int tx = tid & 15, ty = tid >> 4;
        const int r0 = by * 64, c0 = bx * 64;
        const float* src = W1 + ((size_t)bz * DM + r0) * DF + c0;
#pragma unroll
        for (int i = 0; i < 4; ++i) {
            int r = ty + i * 16;
            float4 v = *(const float4*)(src + (size_t)r * DF + tx * 4);
            T[tx * 4 + 0][r] = f2bf(v.x); T[tx * 4 + 1][r] = f2bf(v.y);
            T[tx * 4 + 2][r] = f2bf(v.z); T[tx * 4 + 3][r] = f2bf(v.w);
        }
        __syncthreads();
        unsigned short* dst = W1T + ((size_t)bz * DF + c0) * DM + r0;
#pragma unroll
        for (int i = 0; i < 4; ++i) {
            int c = ty + i * 16;
            ushort4 w;
            w.x = T[c][tx * 4 + 0]; w.y = T[c][tx * 4 + 1];
            w.z = T[c][tx * 4 + 2]; w.w = T[c][tx * 4 + 3];
            *(ushort4*)(dst + (size_t)c * DM + tx * 4) = w;
        }
    } else {  // W2 [E][DF][DM] -> bf16 W2T [E][DM][DF] (fused mode only)
        const int t = b - 3073;
        const int bx = t & 7, by = (t >> 3) & 31, bz = t >> 8;
        const int tx = tid & 15, ty = tid >> 4;
        const int r0 = by * 64, c0 = bx * 64;
        const float* src = W2 + ((size_t)bz * DF + r0) * DM + c0;
#pragma unroll
        for (int i = 0; i < 4; ++i) {
            int r = ty + i * 16;
            float4 v = *(const float4*)(src + (size_t)r * DM + tx * 4);
            T[tx * 4 + 0][r] = f2bf(v.x); T[tx * 4 + 1][r] = f2bf(v.y);
            T[tx * 4 + 2][r] = f2bf(v.z); T[tx * 4 + 3][r] = f2bf(v.w);
        }
        __syncthreads();
        unsigned short* dst = W2T + ((size_t)bz * DM + c0) * DF + r0;
#pragma unroll
        for (int i = 0; i < 4; ++i) {
            int c = ty + i * 16;
            ushort4 w;
            w.x = T[c][tx * 4 + 0]; w.y = T[c][tx * 4 + 1];
            w.z = T[c][tx * 4 + 2]; w.w = T[c][tx * 4 + 3];
            *(ushort4*)(dst + (size_t)c * DF + tx * 4) = w;
        }
    }
}

// ---- W2 [E][DF][DM] -> bf16 W2T [E][DM][DF] (fallback when ws too small to fuse) ----
__global__ void k_tw2(const float* __restrict__ in, unsigned short* __restrict__ out) {
    __shared__ unsigned short T[64][65];
    const int tid = threadIdx.x;
    const int tx = tid & 15, ty = tid >> 4;
    const int r0 = blockIdx.y * 64, c0 = blockIdx.x * 64;
    const float* src = in + ((size_t)blockIdx.z * DF + r0) * DM + c0;
#pragma unroll
    for (int i = 0; i < 4; ++i) {
        int r = ty + i * 16;
        float4 v = *(const float4*)(src + (size_t)r * DM + tx * 4);
        T[tx * 4 + 0][r] = f2bf(v.x); T[tx * 4 + 1][r] = f2bf(v.y);
        T[tx * 4 + 2][r] = f2bf(v.z); T[tx * 4 + 3][r] = f2bf(v.w);
    }
    __syncthreads();
    unsigned short* dst = out + ((size_t)blockIdx.z * DM + c0) * DF + r0;
#pragma unroll
    for (int i = 0; i < 4; ++i) {
        int c = ty + i * 16;
        ushort4 w;
        w.x = T[c][tx * 4 + 0]; w.y = T[c][tx * 4 + 1];
        w.z = T[c][tx * 4 + 2]; w.w = T[c][tx * 4 + 3];
        *(ushort4*)(dst + (size_t)c * DF + tx * 4) = w;
    }
}

// ------ GEMM1: H = gelu(Xb[tok] @ W1), 128x64 tile, 3 blocks/CU, dbuf counted-vmcnt ----
// Grid (nt=32, mt=64, e=8): id%8 = nt%8 -> W1T panels pinned per-XCD (2MB resident).
// LDS 48KB: As 2x16KB + Bs 2x8KB; epilogue reuses As as [128][72] bf16 C-tile.
__launch_bounds__(256, 3)
__global__ void k_gemm1d(const unsigned short* __restrict__ Xb,
                         const unsigned short* __restrict__ W1T,
                         const int* __restrict__ counts, const int* __restrict__ opad,
                         const int* __restrict__ rowmap, unsigned short* __restrict__ H) {
    const int e = blockIdx.z, mt = blockIdx.y, nt = blockIdx.x;
    const int grow = opad[e] + mt * 128;
    int valid = counts[e] - mt * 128;
    if (valid <= 0) return;
    if (valid > 128) valid = 128;

    __shared__ __align__(16) unsigned short As[2][8192];  // A: 128x64 dbuf (32 KB)
    __shared__ __align__(16) unsigned short Bs[2][4096];  // B:  64x64 dbuf (16 KB)
    __shared__ int toks[128];

    const int tid = threadIdx.x;
    if (tid < 128) {
        int i = (tid < valid) ? tid : 0;
        toks[tid] = rowmap[grow + i] >> 1;
    }
    __syncthreads();

    const int wave = tid >> 6, lane = tid & 63;
    const int wm = wave >> 1, wn = wave & 1;
    const int quad = lane >> 4, l15 = lane & 15;

    const unsigned short* ga[4];
    unsigned short* la[4];
#pragma unroll
    for (int j = 0; j < 4; ++j) {
        int row = wave * 32 + j * 8 + (lane >> 3);
        int ch = (lane & 7) ^ ((lane >> 3) & 7);
        ga[j] = Xb + (size_t)toks[row] * DM + ch * 8;
        la[j] = &As[0][(wave * 32 + j * 8) * 64];
    }
    const unsigned short* gb[2];
    unsigned short* lb[2];
#pragma unroll
    for (int j = 0; j < 2; ++j) {
        int row = wave * 16 + j * 8 + (lane >> 3);  // [0,64)
        int ch = (lane & 7) ^ ((lane >> 3) & 7);
        gb[j] = W1T + ((size_t)e * DF + nt * 64 + row) * DM + ch * 8;
        lb[j] = &Bs[0][(wave * 16 + j * 8) * 64];
    }

    f32x4 acc[4][2] = {};

    STAGE2B(0, 0);
#pragma unroll 1
    for (int kt = 0; kt < 8; kt += 2) {
        if (kt + 1 < 8) { STAGE2B(1, (kt + 1) * 64); WAITN(6); } else { WAITN(0); }
        BAR();
        mfma_step2(&As[0][0], &Bs[0][0], wm, wn, quad, l15, acc);
        BAR();
        if (kt + 2 < 8) { STAGE2B(0, (kt + 2) * 64); WAITN(6); } else { WAITN(0); }
        BAR();
        mfma_step2(&As[1][0], &Bs[1][0], wm, wn, quad, l15, acc);
        BAR();
    }

    // ---- epilogue through LDS: bf16 C-tile [128][72], then coalesced 16B stores ----
    unsigned short* ep = &As[0][0];  // 9216 ushorts needed <= 16384 available
#pragma unroll
    for (int fm = 0; fm < 4; ++fm)
#pragma unroll
        for (int i = 0; i < 4; ++i) {
            int r = wm * 64 + fm * 16 + quad * 4 + i;
#pragma unroll
            for (int fn = 0; fn < 2; ++fn)
                ep[r * 72 + wn * 32 + fn * 16 + l15] = f2bf(gelu_fast(acc[fm][fn][i]));
        }
    __syncthreads();
    {
        const int ch = tid & 7, rr0 = tid >> 3;  // 8 chunks x 32 rows per pass
#pragma unroll
        for (int it = 0; it < 4; ++it) {
            int r = it * 32 + rr0;
            uint4 v = *(const uint4*)&ep[r * 72 + ch * 8];
            *(uint4*)(H + (size_t)(grow + r) * DF + nt * 64 + ch * 8) = v;
        }
    }
}

// ------- GEMM2: out = H @ W2 (K=2048, plain stores), 128x64 tile, 2-deep (r20-exact) ---
// Flat 4096-block grid, XCD decode e=id&7: expert e's W2T (2MB) resident in XCD e's L2.
__launch_bounds__(256, 2)
__global__ void k_gemm2d(const unsigned short* __restrict__ H,
                         const unsigned short* __restrict__ W2T,
                         const int* __restrict__ counts, const int* __restrict__ opad,
                         const int* __restrict__ rowmap, float* __restrict__ out) {
    const int id = blockIdx.x;
    const int e = id & 7;
    const int q = id >> 3;            // [0,512)
    const int nt = q >> 6, mt = q & 63;  // nt in [0,8), 64-col slabs
    const int grow = opad[e] + mt * 128;
    int valid = counts[e] - mt * 128;
    if (valid <= 0) return;
    if (valid > 128) valid = 128;

    __shared__ __align__(16) unsigned short As[2][8192];  // A: 128x64 dbuf (32 KB)
    __shared__ __align__(16) unsigned short Bs[2][4096];  // B:  64x64 dbuf (16 KB)
    __shared__ int pairs[128];

    const int tid = threadIdx.x;
    if (tid < 128) pairs[tid] = (tid < valid) ? rowmap[grow + tid] : 0;
    __syncthreads();

    const int wave = tid >> 6, lane = tid & 63;
    const int wm = wave >> 1, wn = wave & 1;
    const int quad = lane >> 4, l15 = lane & 15;

    const unsigned short* ga[4];
    unsigned short* la[4];
#pragma unroll
    for (int j = 0; j < 4; ++j) {
        int row = wave * 32 + j * 8 + (lane >> 3);
        int ch = (lane & 7) ^ ((lane >> 3) & 7);
        int rr = (row < valid) ? row : 0;  // clamp: never read unwritten H (r7 lesson)
        ga[j] = H + (size_t)(grow + rr) * DF + ch * 8;
        la[j] = &As[0][(wave * 32 + j * 8) * 64];
    }
    const unsigned short* gb[2];
    unsigned short* lb[2];
#pragma unroll
    for (int j = 0; j < 2; ++j) {
        int row = wave * 16 + j * 8 + (lane >> 3);  // [0,64)
        int ch = (lane & 7) ^ ((lane >> 3) & 7);
        gb[j] = W2T + ((size_t)e * DM + nt * 64 + row) * DF + ch * 8;
        lb[j] = &Bs[0][(wave * 16 + j * 8) * 64];
    }

    f32x4 acc[4][2] = {};

    STAGE2B(0, 0);
#pragma unroll 1
    for (int kt = 0; kt < 32; kt += 2) {
        if (kt + 1 < 32) { STAGE2B(1, (kt + 1) * 64); WAITN(6); } else { WAITN(0); }
        BAR();
        mfma_step2(&As[0][0], &Bs[0][0], wm, wn, quad, l15, acc);
        BAR();
        if (kt + 2 < 32) { STAGE2B(0, (kt + 2) * 64); WAITN(6); } else { WAITN(0); }
        BAR();
        mfma_step2(&As[1][0], &Bs[1][0], wm, wn, quad, l15, acc);
        BAR();
    }

#pragma unroll
    for (int fm = 0; fm < 4; ++fm) {
#pragma unroll
        for (int i = 0; i < 4; ++i) {
            int m_l = wm * 64 + fm * 16 + quad * 4 + i;
            if (m_l < valid) {
                float* orow = out + (size_t)pairs[m_l] * DM + nt * 64 + wn * 32;
#pragma unroll
                for (int fn = 0; fn < 2; ++fn)
                    orow[fn * 16 + l15] = acc[fm][fn][i];  // exactly-once: plain store
            }
        }
    }
}

extern "C" void kernel_launch(void* const* d_in, const int* in_sizes, int n_in,
                              void* d_out, int out_size, void* d_ws, size_t ws_size,
                              hipStream_t stream) {
    const float* X = (const float*)d_in[0];
    const int* sel = (const int*)d_in[1];
    const float* W1 = (const float*)d_in[3];
    const float* W2 = (const float*)d_in[4];
    float* out = (float*)d_out;
    float* loads_out = out + (size_t)NPAIR * DM;

    int* counts = (int*)d_ws;
    int* opad = counts + 16;
    int* rowmap = counts + 32;
    const size_t hbytes = (size_t)HCAP * DF * 2;
    const size_t xbytes = (size_t)NTOK * DM * 2;
    const size_t w1tbytes = (size_t)NE * DF * DM * 2;
    unsigned short* H = (unsigned short*)((char*)d_ws + 65536);
    unsigned short* Xb = (unsigned short*)((char*)d_ws + 65536 + hbytes);
    unsigned short* WT = (unsigned short*)((char*)d_ws + 65536 + hbytes + xbytes);

    // fused mode: separate W2T buffer -> W2 transpose folds into k_prep, no k_tw2 dispatch
    const bool fused = ws_size >= 65536 + hbytes + xbytes + 2 * w1tbytes;
    unsigned short* W2T = fused ? WT + w1tbytes / 2 : WT;

    hipLaunchKernelGGL(k_prep, dim3(fused ? 5121 : 3073), dim3(256), 0, stream,
                       X, Xb, W1, WT, W2, W2T, sel, counts, opad, rowmap, loads_out);
    hipLaunchKernelGGL(k_gemm1d, dim3(DF / 64, NPAIR / 128, NE), dim3(256), 0, stream,
                       Xb, WT, counts, opad, rowmap, H);
    if (!fused)
        hipLaunchKernelGGL(k_tw2, dim3(DM / 64, DF / 64, NE), dim3(256), 0, stream, W2, WT);
    hipLaunchKernelGGL(k_gemm2d, dim3(4096), dim3(256), 0, stream,
                       H, W2T, counts, opad, rowmap, out);
}